// Round 1
// baseline (779.653 us; speedup 1.0000x reference)
//
#include <hip/hip_runtime.h>
#include <math.h>

// Problem constants (fixed by setup_inputs)
#define NODES_TOT 7424      // 64 * 116
#define EDGES     237568    // NODES_TOT * 32
#define FEAT      64
#define BATCH     64
#define NN        116
#define K1        7424      // FC K dim (= NODES_TOT = BATCH*NN... = NN*FEAT per batch row)
#define N1        7424      // FC1 out
#define N2        13456     // FC2 out (116*116)
#define KSPLIT    4

__device__ __forceinline__ float mish_f(float v) {
    // mish(x) = x * tanh(softplus(x)), stable softplus = max(x,0) + log1p(exp(-|x|))
    float sp = fmaxf(v, 0.0f) + log1pf(expf(-fabsf(v)));
    return v * tanhf(sp);
}

// ---------- CSR build ----------
__global__ void hist_kernel(const int* __restrict__ dst, int* __restrict__ hist) {
    int e = blockIdx.x * 256 + threadIdx.x;
    if (e < EDGES) atomicAdd(&hist[dst[e]], 1);
}

__global__ void scan_kernel(const int* __restrict__ hist, int* __restrict__ row_start,
                            int* __restrict__ cursor) {
    __shared__ int s[1024];
    int t = threadIdx.x;
    int base = t * 8;            // 1024*8 = 8192 >= 7424
    int loc[8];
    int sum = 0;
    #pragma unroll
    for (int c = 0; c < 8; ++c) {
        int idx = base + c;
        int v = (idx < NODES_TOT) ? hist[idx] : 0;
        loc[c] = sum;            // exclusive within chunk
        sum += v;
    }
    s[t] = sum;
    __syncthreads();
    // Hillis-Steele inclusive scan over 1024 partials
    for (int off = 1; off < 1024; off <<= 1) {
        int v = (t >= off) ? s[t - off] : 0;
        __syncthreads();
        s[t] += v;
        __syncthreads();
    }
    int excl = s[t] - sum;       // exclusive block prefix
    #pragma unroll
    for (int c = 0; c < 8; ++c) {
        int idx = base + c;
        if (idx < NODES_TOT) {
            int r = excl + loc[c];
            row_start[idx] = r;
            cursor[idx] = r;
        }
    }
}

__global__ void csr_fill_kernel(const int* __restrict__ src, const int* __restrict__ dst,
                                int* __restrict__ cursor, int* __restrict__ csr_src) {
    int e = blockIdx.x * 256 + threadIdx.x;
    if (e < EDGES) {
        int p = atomicAdd(&cursor[dst[e]], 1);
        csr_src[p] = src[e];
    }
}

// ---------- fused mean-aggregate + SAGE linear + mish ----------
// out[i,f] = mish( b_l[f] + sum_k mean[i,k]*w_l[f,k] + x[i,k]*w_r[f,k] )
__global__ void __launch_bounds__(256) conv_kernel(
        const float* __restrict__ x, const int* __restrict__ csr_src,
        const int* __restrict__ row_start, const int* __restrict__ deg_arr,
        const float* __restrict__ w_l, const float* __restrict__ b_l,
        const float* __restrict__ w_r, float* __restrict__ h_out) {
    __shared__ float wlT[64 * 64];   // [k][f]
    __shared__ float wrT[64 * 64];   // [k][f]
    __shared__ float mv[4][64];
    __shared__ float xv[4][64];
    int t = threadIdx.x;
    // stage transposed weights (once per block)
    for (int i = 0; i < 16; ++i) {
        int idx = t + i * 256;
        int f = idx >> 6, k = idx & 63;
        wlT[k * 64 + f] = w_l[idx];
        wrT[k * 64 + f] = w_r[idx];
    }
    int g = t >> 6, f = t & 63;      // group (node within quad), feature lane
    __syncthreads();
    for (int nb = blockIdx.x * 4; nb < NODES_TOT; nb += gridDim.x * 4) {
        int node = nb + g;
        int deg = deg_arr[node];
        int rs = row_start[node];
        float sum = 0.f;
        for (int e = 0; e < deg; ++e) {
            int s = csr_src[rs + e];           // wave-uniform
            sum += x[s * 64 + f];              // coalesced 256B per edge
        }
        float mean = sum / (float)max(deg, 1);
        mv[g][f] = mean;
        xv[g][f] = x[node * 64 + f];
        __syncthreads();
        float o = b_l[f];
        #pragma unroll
        for (int k = 0; k < 64; ++k) {
            o = fmaf(mv[g][k], wlT[k * 64 + f], o);
            o = fmaf(xv[g][k], wrT[k * 64 + f], o);
        }
        h_out[node * 64 + f] = mish_f(o);
        __syncthreads();
    }
}

// ---------- 64xK -> Kx64 transpose (optional bias+mish) ----------
template <bool MISH>
__global__ void __launch_bounds__(256) transpose_kernel(
        const float* __restrict__ X, const float* __restrict__ bias, float* __restrict__ XT) {
    __shared__ float tile[64][65];
    int t = threadIdx.x;
    int k0 = blockIdx.x * 64;
    for (int i = 0; i < 16; ++i) {
        int id = t + i * 256;
        int m = id >> 6, kk = id & 63;
        float v = X[m * K1 + k0 + kk];
        if (MISH) v = mish_f(v + bias[k0 + kk]);
        tile[m][kk] = v;
    }
    __syncthreads();
    for (int i = 0; i < 16; ++i) {
        int id = t + i * 256;
        int m = id & 63, kk = id >> 6;
        XT[(k0 + kk) * 64 + m] = tile[m][kk];
    }
}

// ---------- fp32 GEMM: C[64][N] += At[K][64]^T * W[N][K]^T  (K-split, atomic acc) ----------
#define BK 32
__global__ void __launch_bounds__(256) gemm_kernel(
        const float* __restrict__ At, const float* __restrict__ W,
        float* __restrict__ C, int K, int N, int klen) {
    __shared__ float As[BK][64];    // [k][m]
    __shared__ float Bs[64][36];    // [n][k], pad 36 (2-way read conflicts = free)
    int t = threadIdx.x;
    int tn = t & 15, tm = t >> 4;
    int n0 = blockIdx.x * 64;
    int kbase = blockIdx.y * klen;
    float acc[4][4] = {};
    for (int kc = 0; kc < klen; kc += BK) {
        int k0 = kbase + kc;
        #pragma unroll
        for (int i = 0; i < 2; ++i) {
            int id = t + i * 256;
            int am = (id & 15) * 4, ak = id >> 4;
            *(float4*)&As[ak][am] = *(const float4*)&At[(k0 + ak) * 64 + am];
        }
        #pragma unroll
        for (int i = 0; i < 2; ++i) {
            int id = t + i * 256;
            int bk = (id & 7) * 4, bn = id >> 3;
            int gn = n0 + bn;
            float4 v = make_float4(0.f, 0.f, 0.f, 0.f);
            if (gn < N) v = *(const float4*)&W[(size_t)gn * K + k0 + bk];
            *(float4*)&Bs[bn][bk] = v;
        }
        __syncthreads();
        #pragma unroll 8
        for (int kk = 0; kk < BK; ++kk) {
            float4 a = *(const float4*)&As[kk][tm * 4];
            float b0 = Bs[tn * 4 + 0][kk];
            float b1 = Bs[tn * 4 + 1][kk];
            float b2 = Bs[tn * 4 + 2][kk];
            float b3 = Bs[tn * 4 + 3][kk];
            acc[0][0] = fmaf(a.x, b0, acc[0][0]);
            acc[0][1] = fmaf(a.x, b1, acc[0][1]);
            acc[0][2] = fmaf(a.x, b2, acc[0][2]);
            acc[0][3] = fmaf(a.x, b3, acc[0][3]);
            acc[1][0] = fmaf(a.y, b0, acc[1][0]);
            acc[1][1] = fmaf(a.y, b1, acc[1][1]);
            acc[1][2] = fmaf(a.y, b2, acc[1][2]);
            acc[1][3] = fmaf(a.y, b3, acc[1][3]);
            acc[2][0] = fmaf(a.z, b0, acc[2][0]);
            acc[2][1] = fmaf(a.z, b1, acc[2][1]);
            acc[2][2] = fmaf(a.z, b2, acc[2][2]);
            acc[2][3] = fmaf(a.z, b3, acc[2][3]);
            acc[3][0] = fmaf(a.w, b0, acc[3][0]);
            acc[3][1] = fmaf(a.w, b1, acc[3][1]);
            acc[3][2] = fmaf(a.w, b2, acc[3][2]);
            acc[3][3] = fmaf(a.w, b3, acc[3][3]);
        }
        __syncthreads();
    }
    #pragma unroll
    for (int mi = 0; mi < 4; ++mi)
        #pragma unroll
        for (int nj = 0; nj < 4; ++nj) {
            int gn = n0 + tn * 4 + nj;
            if (gn < N) atomicAdd(&C[(size_t)(tm * 4 + mi) * N + gn], acc[mi][nj]);
        }
}

// ---------- fused FC2 bias + symmetrize + unit diagonal ----------
__global__ void sym_kernel(const float* __restrict__ C2, const float* __restrict__ fc2_b,
                           float* __restrict__ out) {
    int tid = blockIdx.x * 256 + threadIdx.x;
    if (tid >= BATCH * NN * NN) return;
    int j = tid % NN;
    int r = tid / NN;
    int i = r % NN;
    int b = r / NN;
    float v;
    if (i == j) {
        v = 1.0f;
    } else {
        float a = C2[(size_t)b * N2 + i * NN + j] + fc2_b[i * NN + j];
        float c = C2[(size_t)b * N2 + j * NN + i] + fc2_b[j * NN + i];
        v = 0.5f * (a + c);
    }
    out[tid] = v;
}

extern "C" void kernel_launch(void* const* d_in, const int* in_sizes, int n_in,
                              void* d_out, int out_size, void* d_ws, size_t ws_size,
                              hipStream_t stream) {
    const float* z     = (const float*)d_in[0];
    const int*   edge  = (const int*)d_in[1];   // [2][EDGES]: src row then dst row
    const float* w1_l  = (const float*)d_in[3];
    const float* b1_l  = (const float*)d_in[4];
    const float* w1_r  = (const float*)d_in[5];
    const float* w2_l  = (const float*)d_in[6];
    const float* b2_l  = (const float*)d_in[7];
    const float* w2_r  = (const float*)d_in[8];
    const float* fc1_w = (const float*)d_in[9];
    const float* fc1_b = (const float*)d_in[10];
    const float* fc2_w = (const float*)d_in[11];
    const float* fc2_b = (const float*)d_in[12];
    float* out = (float*)d_out;

    char* ws = (char*)d_ws;
    size_t off = 0;
    auto alloc = [&](size_t bytes) {
        void* p = ws + off;
        off = (off + bytes + 255) & ~(size_t)255;
        return p;
    };
    int*   hist      = (int*)alloc(NODES_TOT * 4);
    int*   row_start = (int*)alloc(NODES_TOT * 4);
    int*   cursor    = (int*)alloc(NODES_TOT * 4);
    int*   csr_src   = (int*)alloc((size_t)EDGES * 4);
    float* h1        = (float*)alloc((size_t)NODES_TOT * 64 * 4);
    float* h2        = (float*)alloc((size_t)NODES_TOT * 64 * 4);
    float* h2T       = (float*)alloc((size_t)NODES_TOT * 64 * 4);
    float* C1        = (float*)alloc((size_t)BATCH * N1 * 4);
    float* hT        = (float*)alloc((size_t)K1 * 64 * 4);
    float* C2        = (float*)alloc((size_t)BATCH * N2 * 4);

    const int* src = edge;
    const int* dst = edge + EDGES;

    hipMemsetAsync(hist, 0, NODES_TOT * 4, stream);
    hist_kernel<<<(EDGES + 255) / 256, 256, 0, stream>>>(dst, hist);
    scan_kernel<<<1, 1024, 0, stream>>>(hist, row_start, cursor);
    csr_fill_kernel<<<(EDGES + 255) / 256, 256, 0, stream>>>(src, dst, cursor, csr_src);

    conv_kernel<<<928, 256, 0, stream>>>(z, csr_src, row_start, hist, w1_l, b1_l, w1_r, h1);
    conv_kernel<<<928, 256, 0, stream>>>(h1, csr_src, row_start, hist, w2_l, b2_l, w2_r, h2);

    transpose_kernel<false><<<116, 256, 0, stream>>>(h2, nullptr, h2T);

    hipMemsetAsync(C1, 0, (size_t)BATCH * N1 * 4, stream);
    gemm_kernel<<<dim3(N1 / 64, KSPLIT), 256, 0, stream>>>(h2T, fc1_w, C1, K1, N1, K1 / KSPLIT);

    transpose_kernel<true><<<116, 256, 0, stream>>>(C1, fc1_b, hT);

    hipMemsetAsync(C2, 0, (size_t)BATCH * N2 * 4, stream);
    gemm_kernel<<<dim3((N2 + 63) / 64, KSPLIT), 256, 0, stream>>>(hT, fc2_w, C2, K1, N2, K1 / KSPLIT);

    sym_kernel<<<(BATCH * NN * NN + 255) / 256, 256, 0, stream>>>(C2, fc2_b, out);
}

// Round 2
// 466.594 us; speedup vs baseline: 1.6709x; 1.6709x over previous
//
#include <hip/hip_runtime.h>
#include <math.h>

// Problem constants (fixed by setup_inputs)
#define NODES_TOT 7424      // 64 * 116
#define EDGES     237568    // NODES_TOT * 32
#define BATCH     64
#define NN        116
#define KDIM      7424      // FC K dim
#define N1        7424      // FC1 out
#define N2        13456     // FC2 out (116*116)
#define KSPLIT    4

typedef __attribute__((ext_vector_type(8))) short bf16x8;
typedef __attribute__((ext_vector_type(4))) float f32x4;
typedef __attribute__((ext_vector_type(4))) short s16x4;

__device__ __forceinline__ float mish_f(float v) {
    float sp = fmaxf(v, 0.0f) + log1pf(expf(-fabsf(v)));
    return v * tanhf(sp);
}

__device__ __forceinline__ unsigned short bf_rne(float f) {
    unsigned u = __float_as_uint(f);
    u += 0x7fffu + ((u >> 16) & 1u);
    return (unsigned short)(u >> 16);
}

// ---------- CSR build ----------
__global__ void hist_kernel(const int* __restrict__ dst, int* __restrict__ hist) {
    int e = blockIdx.x * 256 + threadIdx.x;
    if (e < EDGES) atomicAdd(&hist[dst[e]], 1);
}

__global__ void scan_kernel(const int* __restrict__ hist, int* __restrict__ row_start,
                            int* __restrict__ cursor) {
    __shared__ int s[1024];
    int t = threadIdx.x;
    int base = t * 8;            // 1024*8 = 8192 >= 7424
    int loc[8];
    int sum = 0;
    #pragma unroll
    for (int c = 0; c < 8; ++c) {
        int idx = base + c;
        int v = (idx < NODES_TOT) ? hist[idx] : 0;
        loc[c] = sum;
        sum += v;
    }
    s[t] = sum;
    __syncthreads();
    for (int off = 1; off < 1024; off <<= 1) {
        int v = (t >= off) ? s[t - off] : 0;
        __syncthreads();
        s[t] += v;
        __syncthreads();
    }
    int excl = s[t] - sum;
    #pragma unroll
    for (int c = 0; c < 8; ++c) {
        int idx = base + c;
        if (idx < NODES_TOT) {
            int r = excl + loc[c];
            row_start[idx] = r;
            cursor[idx] = r;
        }
    }
}

__global__ void csr_fill_kernel(const int* __restrict__ src, const int* __restrict__ dst,
                                int* __restrict__ cursor, int* __restrict__ csr_src) {
    int e = blockIdx.x * 256 + threadIdx.x;
    if (e < EDGES) {
        int p = atomicAdd(&cursor[dst[e]], 1);
        csr_src[p] = src[e];
    }
}

// ---------- fused mean-aggregate + SAGE linear + mish ----------
// out[i,f] = mish( b_l[f] + sum_k mean[i,k]*w_l[f,k] + x[i,k]*w_r[f,k] )
// BF template: write output as bf16 (ushort) instead of fp32
template <bool BF>
__global__ void __launch_bounds__(256) conv_kernel(
        const float* __restrict__ x, const int* __restrict__ csr_src,
        const int* __restrict__ row_start, const int* __restrict__ deg_arr,
        const float* __restrict__ w_l, const float* __restrict__ b_l,
        const float* __restrict__ w_r, void* __restrict__ h_out_v) {
    __shared__ float wlT[64 * 64];   // [k][f]
    __shared__ float wrT[64 * 64];   // [k][f]
    __shared__ float mv[4][64];
    __shared__ float xv[4][64];
    int t = threadIdx.x;
    for (int i = 0; i < 16; ++i) {
        int idx = t + i * 256;
        int f = idx >> 6, k = idx & 63;
        wlT[k * 64 + f] = w_l[idx];
        wrT[k * 64 + f] = w_r[idx];
    }
    int g = t >> 6, f = t & 63;
    __syncthreads();
    for (int nb = blockIdx.x * 4; nb < NODES_TOT; nb += gridDim.x * 4) {
        int node = nb + g;
        int deg = deg_arr[node];
        int rs = row_start[node];
        float sum = 0.f;
        for (int e = 0; e < deg; ++e) {
            int s = csr_src[rs + e];
            sum += x[s * 64 + f];
        }
        float mean = sum / (float)max(deg, 1);
        mv[g][f] = mean;
        xv[g][f] = x[node * 64 + f];
        __syncthreads();
        float o = b_l[f];
        #pragma unroll
        for (int k = 0; k < 64; ++k) {
            o = fmaf(mv[g][k], wlT[k * 64 + f], o);
            o = fmaf(xv[g][k], wrT[k * 64 + f], o);
        }
        float m = mish_f(o);
        if (BF) ((unsigned short*)h_out_v)[node * 64 + f] = bf_rne(m);
        else    ((float*)h_out_v)[node * 64 + f] = m;
        __syncthreads();
    }
}

// ---------- bf16-MFMA skinny GEMM: C[64][N] += A[64][KDIM] * W[N][KDIM]^T ----------
// A pre-converted bf16 row-major. W fp32, converted to hi+lo bf16 in-register
// (so W is effectively exact; only A rounding contributes error).
// Block = 256 thr = 4 waves; wave wv owns output cols [bx*64+16wv, +16), all 64 rows.
// W is read exactly once globally, fully coalesced (lanes {l,l+16,l+32,l+48} read
// one row's contiguous 128B). No LDS.
__global__ void __launch_bounds__(256) gemm_mfma(
        const unsigned short* __restrict__ Abf, const float* __restrict__ W,
        float* __restrict__ C, int N, int klen) {
    int t = threadIdx.x;
    int wv = t >> 6;
    int l = t & 63;
    int l15 = l & 15;
    int lk8 = (l >> 4) * 8;          // k-offset for this lane-group
    int n0 = blockIdx.x * 64 + wv * 16;
    int gn = n0 + l15;               // output col / W row streamed by this lane
    const float* wrow = W + (size_t)(gn < N ? gn : N - 1) * KDIM;
    const unsigned short* ap = Abf + (size_t)l15 * KDIM + lk8;
    f32x4 acc0 = {0.f,0.f,0.f,0.f}, acc1 = {0.f,0.f,0.f,0.f};
    f32x4 acc2 = {0.f,0.f,0.f,0.f}, acc3 = {0.f,0.f,0.f,0.f};
    int kbase = blockIdx.y * klen;
    for (int kc = 0; kc < klen; kc += 32) {
        int k0 = kbase + kc;
        f32x4 w0 = *(const f32x4*)(wrow + k0 + lk8);
        f32x4 w1 = *(const f32x4*)(wrow + k0 + lk8 + 4);
        bf16x8 bhi, blo;
        #pragma unroll
        for (int j = 0; j < 4; ++j) {
            float fv = w0[j];
            unsigned short h = bf_rne(fv);
            float hf = __uint_as_float((unsigned)h << 16);
            bhi[j] = (short)h;
            blo[j] = (short)bf_rne(fv - hf);
        }
        #pragma unroll
        for (int j = 0; j < 4; ++j) {
            float fv = w1[j];
            unsigned short h = bf_rne(fv);
            float hf = __uint_as_float((unsigned)h << 16);
            bhi[4 + j] = (short)h;
            blo[4 + j] = (short)bf_rne(fv - hf);
        }
        bf16x8 a0 = *(const bf16x8*)(ap + (size_t)0  * KDIM + k0);
        bf16x8 a1 = *(const bf16x8*)(ap + (size_t)16 * KDIM + k0);
        bf16x8 a2 = *(const bf16x8*)(ap + (size_t)32 * KDIM + k0);
        bf16x8 a3 = *(const bf16x8*)(ap + (size_t)48 * KDIM + k0);
        acc0 = __builtin_amdgcn_mfma_f32_16x16x32_bf16(a0, bhi, acc0, 0, 0, 0);
        acc0 = __builtin_amdgcn_mfma_f32_16x16x32_bf16(a0, blo, acc0, 0, 0, 0);
        acc1 = __builtin_amdgcn_mfma_f32_16x16x32_bf16(a1, bhi, acc1, 0, 0, 0);
        acc1 = __builtin_amdgcn_mfma_f32_16x16x32_bf16(a1, blo, acc1, 0, 0, 0);
        acc2 = __builtin_amdgcn_mfma_f32_16x16x32_bf16(a2, bhi, acc2, 0, 0, 0);
        acc2 = __builtin_amdgcn_mfma_f32_16x16x32_bf16(a2, blo, acc2, 0, 0, 0);
        acc3 = __builtin_amdgcn_mfma_f32_16x16x32_bf16(a3, bhi, acc3, 0, 0, 0);
        acc3 = __builtin_amdgcn_mfma_f32_16x16x32_bf16(a3, blo, acc3, 0, 0, 0);
    }
    if (gn < N) {
        int rbase = (l >> 4) * 4;    // D row = (lane>>4)*4 + reg  (m89-verified)
        #pragma unroll
        for (int g = 0; g < 4; ++g) atomicAdd(&C[(size_t)( 0 + rbase + g) * N + gn], acc0[g]);
        #pragma unroll
        for (int g = 0; g < 4; ++g) atomicAdd(&C[(size_t)(16 + rbase + g) * N + gn], acc1[g]);
        #pragma unroll
        for (int g = 0; g < 4; ++g) atomicAdd(&C[(size_t)(32 + rbase + g) * N + gn], acc2[g]);
        #pragma unroll
        for (int g = 0; g < 4; ++g) atomicAdd(&C[(size_t)(48 + rbase + g) * N + gn], acc3[g]);
    }
}

// ---------- FC1 epilogue: bias + mish + cast to bf16 (A for FC2) ----------
__global__ void mishcast_kernel(const float* __restrict__ C1, const float* __restrict__ b,
                                unsigned short* __restrict__ A2) {
    int tid = blockIdx.x * 256 + threadIdx.x;
    int i4 = tid * 4;
    if (i4 >= BATCH * N1) return;
    int n = i4 % N1;                 // N1 % 4 == 0 so bias index aligned
    f32x4 c = *(const f32x4*)(C1 + i4);
    f32x4 bb = *(const f32x4*)(b + n);
    s16x4 o;
    #pragma unroll
    for (int j = 0; j < 4; ++j) o[j] = (short)bf_rne(mish_f(c[j] + bb[j]));
    *(s16x4*)(A2 + i4) = o;
}

// ---------- fused FC2 bias + symmetrize + unit diagonal ----------
__global__ void sym_kernel(const float* __restrict__ C2, const float* __restrict__ fc2_b,
                           float* __restrict__ out) {
    int tid = blockIdx.x * 256 + threadIdx.x;
    if (tid >= BATCH * NN * NN) return;
    int j = tid % NN;
    int r = tid / NN;
    int i = r % NN;
    int b = r / NN;
    float v;
    if (i == j) {
        v = 1.0f;
    } else {
        float a = C2[(size_t)b * N2 + i * NN + j] + fc2_b[i * NN + j];
        float c = C2[(size_t)b * N2 + j * NN + i] + fc2_b[j * NN + i];
        v = 0.5f * (a + c);
    }
    out[tid] = v;
}

extern "C" void kernel_launch(void* const* d_in, const int* in_sizes, int n_in,
                              void* d_out, int out_size, void* d_ws, size_t ws_size,
                              hipStream_t stream) {
    const float* z     = (const float*)d_in[0];
    const int*   edge  = (const int*)d_in[1];   // [2][EDGES]: src row then dst row
    const float* w1_l  = (const float*)d_in[3];
    const float* b1_l  = (const float*)d_in[4];
    const float* w1_r  = (const float*)d_in[5];
    const float* w2_l  = (const float*)d_in[6];
    const float* b2_l  = (const float*)d_in[7];
    const float* w2_r  = (const float*)d_in[8];
    const float* fc1_w = (const float*)d_in[9];
    const float* fc1_b = (const float*)d_in[10];
    const float* fc2_w = (const float*)d_in[11];
    const float* fc2_b = (const float*)d_in[12];
    float* out = (float*)d_out;

    char* ws = (char*)d_ws;
    size_t off = 0;
    auto alloc = [&](size_t bytes) {
        void* p = ws + off;
        off = (off + bytes + 255) & ~(size_t)255;
        return p;
    };
    int*            hist      = (int*)alloc(NODES_TOT * 4);
    int*            row_start = (int*)alloc(NODES_TOT * 4);
    int*            cursor    = (int*)alloc(NODES_TOT * 4);
    int*            csr_src   = (int*)alloc((size_t)EDGES * 4);
    float*          h1        = (float*)alloc((size_t)NODES_TOT * 64 * 4);
    unsigned short* A1        = (unsigned short*)alloc((size_t)NODES_TOT * 64 * 2);
    float*          C1        = (float*)alloc((size_t)BATCH * N1 * 4);
    unsigned short* A2        = (unsigned short*)alloc((size_t)BATCH * N1 * 2);
    float*          C2        = (float*)alloc((size_t)BATCH * N2 * 4);

    const int* src = edge;
    const int* dst = edge + EDGES;

    hipMemsetAsync(hist, 0, NODES_TOT * 4, stream);
    hist_kernel<<<(EDGES + 255) / 256, 256, 0, stream>>>(dst, hist);
    scan_kernel<<<1, 1024, 0, stream>>>(hist, row_start, cursor);
    csr_fill_kernel<<<(EDGES + 255) / 256, 256, 0, stream>>>(src, dst, cursor, csr_src);

    conv_kernel<false><<<928, 256, 0, stream>>>(z, csr_src, row_start, hist, w1_l, b1_l, w1_r, h1);
    conv_kernel<true><<<928, 256, 0, stream>>>(h1, csr_src, row_start, hist, w2_l, b2_l, w2_r, A1);

    // FC1: C1[64][7424] = A1 * fc1_w^T
    hipMemsetAsync(C1, 0, (size_t)BATCH * N1 * 4, stream);
    gemm_mfma<<<dim3(N1 / 64, KSPLIT), 256, 0, stream>>>(A1, fc1_w, C1, N1, KDIM / KSPLIT);

    mishcast_kernel<<<(BATCH * N1 / 4 + 255) / 256, 256, 0, stream>>>(C1, fc1_b, A2);

    // FC2: C2[64][13456] = A2 * fc2_w^T
    hipMemsetAsync(C2, 0, (size_t)BATCH * N2 * 4, stream);
    gemm_mfma<<<dim3((N2 + 63) / 64, KSPLIT), 256, 0, stream>>>(A2, fc2_w, C2, N2, KDIM / KSPLIT);

    sym_kernel<<<(BATCH * NN * NN + 255) / 256, 256, 0, stream>>>(C2, fc2_b, out);
}

// Round 3
// 329.919 us; speedup vs baseline: 2.3632x; 1.4143x over previous
//
#include <hip/hip_runtime.h>
#include <math.h>

// Problem constants (fixed by setup_inputs)
#define NODES_TOT 7424      // 64 * 116
#define EDGES     237568    // NODES_TOT * 32
#define BATCH     64
#define NN        116
#define KDIM      7424      // FC K dim
#define N1        7424      // FC1 out
#define N2        13456     // FC2 out (116*116)
#define KSPLIT    8
#define NKB       116       // KDIM / 64 k-steps total

typedef __attribute__((ext_vector_type(8))) short bf16x8;
typedef __attribute__((ext_vector_type(4))) float f32x4;
typedef __attribute__((ext_vector_type(4))) short s16x4;

__device__ __forceinline__ float mish_f(float v) {
    float sp = fmaxf(v, 0.0f) + log1pf(expf(-fabsf(v)));
    return v * tanhf(sp);
}

__device__ __forceinline__ unsigned short bf_rne(float f) {
    unsigned u = __float_as_uint(f);
    u += 0x7fffu + ((u >> 16) & 1u);
    return (unsigned short)(u >> 16);
}

// ---------- small utility ----------
__global__ void zero_kernel(int* __restrict__ p, int n) {
    int i = blockIdx.x * 256 + threadIdx.x;
    if (i < n) p[i] = 0;
}

// ---------- CSR build ----------
__global__ void hist_kernel(const int* __restrict__ dst, int* __restrict__ hist) {
    int e = blockIdx.x * 256 + threadIdx.x;
    if (e < EDGES) atomicAdd(&hist[dst[e]], 1);
}

__global__ void scan_kernel(const int* __restrict__ hist, int* __restrict__ row_start,
                            int* __restrict__ cursor) {
    __shared__ int s[1024];
    int t = threadIdx.x;
    int base = t * 8;
    int loc[8];
    int sum = 0;
    #pragma unroll
    for (int c = 0; c < 8; ++c) {
        int idx = base + c;
        int v = (idx < NODES_TOT) ? hist[idx] : 0;
        loc[c] = sum;
        sum += v;
    }
    s[t] = sum;
    __syncthreads();
    for (int off = 1; off < 1024; off <<= 1) {
        int v = (t >= off) ? s[t - off] : 0;
        __syncthreads();
        s[t] += v;
        __syncthreads();
    }
    int excl = s[t] - sum;
    #pragma unroll
    for (int c = 0; c < 8; ++c) {
        int idx = base + c;
        if (idx < NODES_TOT) {
            int r = excl + loc[c];
            row_start[idx] = r;
            cursor[idx] = r;
        }
    }
}

__global__ void csr_fill_kernel(const int* __restrict__ src, const int* __restrict__ dst,
                                int* __restrict__ cursor, int* __restrict__ csr_src) {
    int e = blockIdx.x * 256 + threadIdx.x;
    if (e < EDGES) {
        int p = atomicAdd(&cursor[dst[e]], 1);
        csr_src[p] = src[e];
    }
}

// ---------- fused mean-aggregate + SAGE linear + mish ----------
template <bool BF>
__global__ void __launch_bounds__(256) conv_kernel(
        const float* __restrict__ x, const int* __restrict__ csr_src,
        const int* __restrict__ row_start, const int* __restrict__ deg_arr,
        const float* __restrict__ w_l, const float* __restrict__ b_l,
        const float* __restrict__ w_r, void* __restrict__ h_out_v) {
    __shared__ float wlT[64 * 64];   // [k][f]
    __shared__ float wrT[64 * 64];   // [k][f]
    __shared__ float mv[4][64];
    __shared__ float xv[4][64];
    int t = threadIdx.x;
    for (int i = 0; i < 16; ++i) {
        int idx = t + i * 256;
        int f = idx >> 6, k = idx & 63;
        wlT[k * 64 + f] = w_l[idx];
        wrT[k * 64 + f] = w_r[idx];
    }
    int g = t >> 6, f = t & 63;
    __syncthreads();
    for (int nb = blockIdx.x * 4; nb < NODES_TOT; nb += gridDim.x * 4) {
        int node = nb + g;
        int deg = deg_arr[node];
        int rs = row_start[node];
        float sum = 0.f;
        for (int e = 0; e < deg; ++e) {
            int s = csr_src[rs + e];
            sum += x[s * 64 + f];
        }
        float mean = sum / (float)max(deg, 1);
        mv[g][f] = mean;
        xv[g][f] = x[node * 64 + f];
        __syncthreads();
        float o = b_l[f];
        #pragma unroll
        for (int k = 0; k < 64; ++k) {
            o = fmaf(mv[g][k], wlT[k * 64 + f], o);
            o = fmaf(xv[g][k], wrT[k * 64 + f], o);
        }
        float m = mish_f(o);
        if (BF) ((unsigned short*)h_out_v)[node * 64 + f] = bf_rne(m);
        else    ((float*)h_out_v)[node * 64 + f] = m;
        __syncthreads();
    }
}

// ---------- bf16-MFMA tiled GEMM: Cp[by][64][N] = A[64][Kslice] * W[N-tile][Kslice]^T ----------
// LDS fragment-ordered layout: 16B chunk index = f*64 + (tilerow ^ (f&7)),
// f = k-chunk-of-8 within the 64-k step (0..7). XOR spreads bank-quads evenly
// for both staging ds_writes and fragment ds_reads.
__global__ void __launch_bounds__(256) gemm_tile(
        const unsigned short* __restrict__ Abf, const float* __restrict__ W,
        float* __restrict__ Cp, int N) {
    __shared__ __align__(16) short Whi[512 * 8];
    __shared__ __align__(16) short Wlo[512 * 8];
    __shared__ __align__(16) short Ash[512 * 8];
    int t = threadIdx.x;
    int bx = blockIdx.x, by = blockIdx.y;
    int kb0 = (by * NKB) >> 3;          // KSPLIT=8 slices of the 116 k-steps
    int kb1 = ((by + 1) * NKB) >> 3;
    int n0 = bx * 64;
    // staging indices: thread covers row (t>>2), k-quarter (t&3) (16 of 64 k)
    int srow = t >> 2;
    int scq = t & 3;
    int wr = n0 + srow; if (wr >= N) wr = N - 1;
    const float* wsrc = W + (size_t)wr * KDIM + scq * 16;
    const unsigned short* asrc = Abf + (size_t)srow * KDIM + scq * 16;
    int f0 = scq * 2, f1 = f0 + 1;
    int c0 = (f0 * 64 + (srow ^ (f0 & 7))) * 8;   // short index of 16B chunk
    int c1 = (f1 * 64 + (srow ^ (f1 & 7))) * 8;
    // compute indices
    int wv = t >> 6, l = t & 63, l15 = l & 15, hi = l >> 4;
    f32x4 acc[4];
    #pragma unroll
    for (int g = 0; g < 4; ++g) acc[g] = (f32x4){0.f, 0.f, 0.f, 0.f};

    // prologue: load first k-step
    size_t k0 = (size_t)kb0 * 64;
    f32x4 w0 = *(const f32x4*)(wsrc + k0);
    f32x4 w1 = *(const f32x4*)(wsrc + k0 + 4);
    f32x4 w2 = *(const f32x4*)(wsrc + k0 + 8);
    f32x4 w3 = *(const f32x4*)(wsrc + k0 + 12);
    bf16x8 a0 = *(const bf16x8*)(asrc + k0);
    bf16x8 a1 = *(const bf16x8*)(asrc + k0 + 8);

    for (int kb = kb0; kb < kb1; ++kb) {
        // convert current W 16 floats -> hi/lo bf16
        bf16x8 h0, l0, h1, l1;
        #pragma unroll
        for (int j = 0; j < 4; ++j) {
            float fv = w0[j];
            unsigned short h = bf_rne(fv);
            h0[j] = (short)h;
            l0[j] = (short)bf_rne(fv - __uint_as_float((unsigned)h << 16));
            fv = w1[j];
            h = bf_rne(fv);
            h0[4 + j] = (short)h;
            l0[4 + j] = (short)bf_rne(fv - __uint_as_float((unsigned)h << 16));
            fv = w2[j];
            h = bf_rne(fv);
            h1[j] = (short)h;
            l1[j] = (short)bf_rne(fv - __uint_as_float((unsigned)h << 16));
            fv = w3[j];
            h = bf_rne(fv);
            h1[4 + j] = (short)h;
            l1[4 + j] = (short)bf_rne(fv - __uint_as_float((unsigned)h << 16));
        }
        __syncthreads();   // previous iter's reads complete before overwrite
        *(bf16x8*)&Whi[c0] = h0;
        *(bf16x8*)&Wlo[c0] = l0;
        *(bf16x8*)&Whi[c1] = h1;
        *(bf16x8*)&Wlo[c1] = l1;
        *(bf16x8*)&Ash[c0] = a0;
        *(bf16x8*)&Ash[c1] = a1;
        __syncthreads();
        // prefetch next k-step while MFMAs run
        if (kb + 1 < kb1) {
            size_t kn = (size_t)(kb + 1) * 64;
            w0 = *(const f32x4*)(wsrc + kn);
            w1 = *(const f32x4*)(wsrc + kn + 4);
            w2 = *(const f32x4*)(wsrc + kn + 8);
            w3 = *(const f32x4*)(wsrc + kn + 12);
            a0 = *(const bf16x8*)(asrc + kn);
            a1 = *(const bf16x8*)(asrc + kn + 8);
        }
        #pragma unroll
        for (int s = 0; s < 2; ++s) {
            int fw = s * 4 + hi;
            int wc = (fw * 64 + ((wv * 16 + l15) ^ (fw & 7))) * 8;
            bf16x8 bh = *(const bf16x8*)&Whi[wc];
            bf16x8 bl = *(const bf16x8*)&Wlo[wc];
            #pragma unroll
            for (int g = 0; g < 4; ++g) {
                int ac = (fw * 64 + ((g * 16 + l15) ^ (fw & 7))) * 8;
                bf16x8 av = *(const bf16x8*)&Ash[ac];
                acc[g] = __builtin_amdgcn_mfma_f32_16x16x32_bf16(av, bh, acc[g], 0, 0, 0);
                acc[g] = __builtin_amdgcn_mfma_f32_16x16x32_bf16(av, bl, acc[g], 0, 0, 0);
            }
        }
    }
    // store partials (no atomics)
    int gn = n0 + wv * 16 + l15;
    if (gn < N) {
        float* cp = Cp + (size_t)by * 64 * N;
        #pragma unroll
        for (int g = 0; g < 4; ++g)
            #pragma unroll
            for (int r = 0; r < 4; ++r)
                cp[(size_t)(g * 16 + hi * 4 + r) * N + gn] = acc[g][r];
    }
}

// ---------- reduce KSPLIT partials + bias + mish + bf16 cast (FC1 epilogue) ----------
__global__ void reduce1_kernel(const float* __restrict__ Cp, const float* __restrict__ b,
                               unsigned short* __restrict__ A2) {
    int i4 = (blockIdx.x * 256 + threadIdx.x) * 4;
    if (i4 >= BATCH * N1) return;
    int n = i4 % N1;
    f32x4 acc = *(const f32x4*)(b + n);
    #pragma unroll
    for (int s = 0; s < KSPLIT; ++s)
        acc += *(const f32x4*)(Cp + (size_t)s * BATCH * N1 + i4);
    s16x4 o;
    #pragma unroll
    for (int j = 0; j < 4; ++j) o[j] = (short)bf_rne(mish_f(acc[j]));
    *(s16x4*)(A2 + i4) = o;
}

// ---------- reduce KSPLIT partials + bias (FC2 epilogue) ----------
__global__ void reduce2_kernel(const float* __restrict__ Cp, const float* __restrict__ b,
                               float* __restrict__ C2) {
    int i4 = (blockIdx.x * 256 + threadIdx.x) * 4;
    if (i4 >= BATCH * N2) return;
    int n = i4 % N2;
    f32x4 acc = *(const f32x4*)(b + n);
    #pragma unroll
    for (int s = 0; s < KSPLIT; ++s)
        acc += *(const f32x4*)(Cp + (size_t)s * BATCH * N2 + i4);
    *(f32x4*)(C2 + i4) = acc;
}

// ---------- symmetrize + unit diagonal (C2 is L2-resident, bias pre-added) ----------
__global__ void sym_kernel(const float* __restrict__ C2, float* __restrict__ out) {
    int tid = blockIdx.x * 256 + threadIdx.x;
    if (tid >= BATCH * NN * NN) return;
    int j = tid % NN;
    int r = tid / NN;
    int i = r % NN;
    int b = r / NN;
    float v;
    if (i == j) {
        v = 1.0f;
    } else {
        v = 0.5f * (C2[(size_t)b * N2 + i * NN + j] + C2[(size_t)b * N2 + j * NN + i]);
    }
    out[tid] = v;
}

extern "C" void kernel_launch(void* const* d_in, const int* in_sizes, int n_in,
                              void* d_out, int out_size, void* d_ws, size_t ws_size,
                              hipStream_t stream) {
    const float* z     = (const float*)d_in[0];
    const int*   edge  = (const int*)d_in[1];
    const float* w1_l  = (const float*)d_in[3];
    const float* b1_l  = (const float*)d_in[4];
    const float* w1_r  = (const float*)d_in[5];
    const float* w2_l  = (const float*)d_in[6];
    const float* b2_l  = (const float*)d_in[7];
    const float* w2_r  = (const float*)d_in[8];
    const float* fc1_w = (const float*)d_in[9];
    const float* fc1_b = (const float*)d_in[10];
    const float* fc2_w = (const float*)d_in[11];
    const float* fc2_b = (const float*)d_in[12];
    float* out = (float*)d_out;

    char* ws = (char*)d_ws;
    size_t off = 0;
    auto alloc = [&](size_t bytes) {
        void* p = ws + off;
        off = (off + bytes + 255) & ~(size_t)255;
        return p;
    };
    int*            hist      = (int*)alloc(NODES_TOT * 4);
    int*            row_start = (int*)alloc(NODES_TOT * 4);
    int*            cursor    = (int*)alloc(NODES_TOT * 4);
    int*            csr_src   = (int*)alloc((size_t)EDGES * 4);
    float*          h1        = (float*)alloc((size_t)NODES_TOT * 64 * 4);
    unsigned short* A1        = (unsigned short*)alloc((size_t)NODES_TOT * 64 * 2);
    float*          Cp1       = (float*)alloc((size_t)KSPLIT * BATCH * N1 * 4);
    unsigned short* A2        = (unsigned short*)alloc((size_t)BATCH * N1 * 2);
    float*          Cp2       = (float*)alloc((size_t)KSPLIT * BATCH * N2 * 4);
    float*          C2        = (float*)alloc((size_t)BATCH * N2 * 4);

    const int* src = edge;
    const int* dst = edge + EDGES;

    zero_kernel<<<(NODES_TOT + 255) / 256, 256, 0, stream>>>(hist, NODES_TOT);
    hist_kernel<<<(EDGES + 255) / 256, 256, 0, stream>>>(dst, hist);
    scan_kernel<<<1, 1024, 0, stream>>>(hist, row_start, cursor);
    csr_fill_kernel<<<(EDGES + 255) / 256, 256, 0, stream>>>(src, dst, cursor, csr_src);

    conv_kernel<false><<<928, 256, 0, stream>>>(z, csr_src, row_start, hist, w1_l, b1_l, w1_r, h1);
    conv_kernel<true><<<928, 256, 0, stream>>>(h1, csr_src, row_start, hist, w2_l, b2_l, w2_r, A1);

    // FC1: partials over k-splits, then fused reduce+bias+mish+cast
    gemm_tile<<<dim3(N1 / 64, KSPLIT), 256, 0, stream>>>(A1, fc1_w, Cp1, N1);
    reduce1_kernel<<<(BATCH * N1 / 4 + 255) / 256, 256, 0, stream>>>(Cp1, fc1_b, A2);

    // FC2
    gemm_tile<<<dim3((N2 + 63) / 64, KSPLIT), 256, 0, stream>>>(A2, fc2_w, Cp2, N2);
    reduce2_kernel<<<(BATCH * N2 / 4 + 255) / 256, 256, 0, stream>>>(Cp2, fc2_b, C2);

    sym_kernel<<<(BATCH * NN * NN + 255) / 256, 256, 0, stream>>>(C2, out);
}